// Round 2
// baseline (172.388 us; speedup 1.0000x reference)
//
#include <hip/hip_runtime.h>
#include <hip/hip_bf16.h>
#include <stdint.h>

#define DM 1024
#define HD 128
#define NH 8
#define NB 2
#define TGT 1024
#define SRC 8192
#define JPH 1024
#define LOG2E 1.4426950408889634f

typedef __attribute__((ext_vector_type(8))) short bf16x8;
typedef __attribute__((ext_vector_type(4))) float f32x4;

__device__ __forceinline__ unsigned short f2bf(float f) {
  __hip_bfloat16 h = __float2bfloat16(f);
  return __builtin_bit_cast(unsigned short, h);
}

__device__ __forceinline__ void gload_lds16(const void* g, void* l) {
  __builtin_amdgcn_global_load_lds(
      (const __attribute__((address_space(1))) unsigned int*)g,
      (__attribute__((address_space(3))) unsigned int*)l, 16, 0, 0);
}

// ---------------------------------------------------------------------------
// Weight transpose + fp32->bf16 convert: WT[n][k] = bf16(W[k][n])
// grid (16,16,4) block 256
// ---------------------------------------------------------------------------
__global__ __launch_bounds__(256) void wconv_kernel(
    const float* __restrict__ Wq, const float* __restrict__ Wk,
    const float* __restrict__ Wv, const float* __restrict__ Wo,
    unsigned short* __restrict__ WTout) {
  __shared__ float tile[64][65];
  const float* W = (blockIdx.z == 0) ? Wq : (blockIdx.z == 1) ? Wk
                   : (blockIdx.z == 2) ? Wv : Wo;
  unsigned short* WT = WTout + (size_t)blockIdx.z * DM * DM;
  const int k0 = blockIdx.x * 64, n0 = blockIdx.y * 64;
  const int tid = threadIdx.x;
  const int tr = tid >> 4, tc = (tid & 15) * 4;
  for (int it = 0; it < 4; ++it) {
    int r = tr + it * 16;
    float4 vv = *(const float4*)(&W[(size_t)(k0 + r) * DM + n0 + tc]);
    tile[r][tc] = vv.x; tile[r][tc + 1] = vv.y;
    tile[r][tc + 2] = vv.z; tile[r][tc + 3] = vv.w;
  }
  __syncthreads();
  for (int it = 0; it < 4; ++it) {
    int n = tr + it * 16;
    ushort4 o;
    o.x = f2bf(tile[tc + 0][n]); o.y = f2bf(tile[tc + 1][n]);
    o.z = f2bf(tile[tc + 2][n]); o.w = f2bf(tile[tc + 3][n]);
    *(ushort4*)(&WT[(size_t)(n0 + n) * DM + k0 + tc]) = o;
  }
}

// ---------------------------------------------------------------------------
// Projection GEMM, fp32 A with inline bf16 conversion, bf16 W^T as B.
// mode 0: Q  = q @ Wq + bq, scaled 1/sqrt(128), -> Qp[b][h][t][d]
//         grid: x = n-tile (8), y = m-tile (16)
// mode 1: K  = k[j=h+8j'] @ Wk[:,h*128..] + bk -> Kp[bh][j'][d]
// mode 2: V  = v[j=h+8j'] @ Wv[:,h*128..] + bv -> VpT[bh][d][j']
//         grid: x = m-tile (8), y = bh (16)
// ---------------------------------------------------------------------------
__global__ __launch_bounds__(256) void proj_kernel(
    const float* __restrict__ q, const float* __restrict__ k,
    const float* __restrict__ v, const unsigned short* __restrict__ WTall,
    const float* __restrict__ bq, const float* __restrict__ bk,
    const float* __restrict__ bv, unsigned short* __restrict__ Qp,
    unsigned short* __restrict__ Kp, unsigned short* __restrict__ VpT,
    int mode) {
  __shared__ unsigned short Alds[128 * 40];
  __shared__ unsigned short Blds[128 * 40];
  const int tid = threadIdx.x, lane = tid & 63, w = tid >> 6;
  const int wm = w >> 1, wn = w & 1;
  const int l15 = lane & 15, l4 = lane >> 4;

  const float* Asrc;
  const unsigned short* WT;
  const float* bias;
  int nbase, bh = 0, Mtile;
  if (mode == 0) {
    Asrc = q; WT = WTall; bias = bq;
    Mtile = blockIdx.y; nbase = blockIdx.x * 128;
  } else {
    bh = blockIdx.y; Mtile = blockIdx.x;
    nbase = (bh & 7) * 128;
    if (mode == 1) { Asrc = k; WT = WTall + (size_t)1 * DM * DM; bias = bk; }
    else           { Asrc = v; WT = WTall + (size_t)2 * DM * DM; bias = bv; }
  }

  f32x4 acc[4][4] = {};

  for (int k0 = 0; k0 < DM; k0 += 32) {
    {  // stage A (fp32 -> bf16)
      const int c4 = (tid & 7) * 4;
      const int rbase = tid >> 3;
      for (int it = 0; it < 4; ++it) {
        int r = rbase + it * 32;
        size_t row;
        if (mode == 0) row = (size_t)(Mtile * 128 + r);
        else row = (size_t)(bh >> 3) * SRC + (bh & 7) + 8u * (Mtile * 128 + r);
        float4 va = *(const float4*)(&Asrc[row * DM + k0 + c4]);
        ushort4 wa;
        wa.x = f2bf(va.x); wa.y = f2bf(va.y);
        wa.z = f2bf(va.z); wa.w = f2bf(va.w);
        *(ushort4*)(&Alds[r * 40 + c4]) = wa;
      }
    }
    {  // stage B (already bf16, W^T rows n)
      const int c8 = (tid & 3) * 8;
      const int nb_ = tid >> 2;
      for (int it = 0; it < 2; ++it) {
        int n = nb_ + it * 64;
        *(uint4*)(&Blds[n * 40 + c8]) =
            *(const uint4*)(&WT[(size_t)(nbase + n) * DM + k0 + c8]);
      }
    }
    __syncthreads();
    bf16x8 af[4], bfr[4];
    for (int f = 0; f < 4; ++f) {
      af[f]  = *(const bf16x8*)(&Alds[(wm * 64 + f * 16 + l15) * 40 + l4 * 8]);
      bfr[f] = *(const bf16x8*)(&Blds[(wn * 64 + f * 16 + l15) * 40 + l4 * 8]);
    }
    for (int fm = 0; fm < 4; ++fm)
      for (int fn = 0; fn < 4; ++fn)
        acc[fm][fn] = __builtin_amdgcn_mfma_f32_16x16x32_bf16(
            af[fm], bfr[fn], acc[fm][fn], 0, 0, 0);
    __syncthreads();
  }

  // epilogue
  for (int fm = 0; fm < 4; ++fm) {
    for (int fn = 0; fn < 4; ++fn) {
      const int mloc = wm * 64 + fm * 16 + l4 * 4;
      const int nloc = wn * 64 + fn * 16 + l15;
      const float bs = bias[nbase + nloc];
      if (mode == 2) {
        const int d = nloc;
        const int jp = Mtile * 128 + mloc;
        ushort4 o;
        o.x = f2bf(acc[fm][fn][0] + bs); o.y = f2bf(acc[fm][fn][1] + bs);
        o.z = f2bf(acc[fm][fn][2] + bs); o.w = f2bf(acc[fm][fn][3] + bs);
        *(ushort4*)(&VpT[((size_t)bh * HD + d) * JPH + jp]) = o;
      } else if (mode == 1) {
        for (int i = 0; i < 4; ++i) {
          int jp = Mtile * 128 + mloc + i;
          Kp[((size_t)bh * JPH + jp) * HD + nloc] = f2bf(acc[fm][fn][i] + bs);
        }
      } else {
        for (int i = 0; i < 4; ++i) {
          int mg = Mtile * 128 + mloc + i;
          int bb = mg >> 10, t = mg & 1023;
          int ng = nbase + nloc;
          int h = ng >> 7, d = ng & 127;
          Qp[(((size_t)bb * NH + h) * TGT + t) * HD + d] =
              f2bf((acc[fm][fn][i] + bs) * 0.08838834764831845f);
        }
      }
    }
  }
}

// ---------------------------------------------------------------------------
// Flash attention per (b,h), sparse j = h + 8*j'. grid (16 tq, 16 bh), 256 thr
// Swapped QK^T: mfma(A=K, B=Q) -> lane owns one query row's scores (t=lane&15).
// NOTE: acc_o rows are t=(lane>>4)*4+i (C/D layout) -> alpha must be
// shfl-broadcast from the lane owning that row's softmax state.
// ---------------------------------------------------------------------------
__global__ __launch_bounds__(256) void attn_kernel(
    const unsigned short* __restrict__ Qp, const unsigned short* __restrict__ Kp,
    const unsigned short* __restrict__ VpT, unsigned short* __restrict__ O) {
  __shared__ unsigned short Klds[64 * 128];   // [j][d] swizzled, 16 KB
  __shared__ unsigned short Vlds[128 * 64];   // [d][j] swizzled, 16 KB
  __shared__ unsigned short Plds[4 * 16 * 64];// per-wave [t][j] swizzled, 8 KB
  const int tid = threadIdx.x, lane = tid & 63, w = tid >> 6;
  const int tq = blockIdx.x, bh = blockIdx.y;
  const int T0 = tq * 64 + w * 16;
  const int l15 = lane & 15, l4 = lane >> 4;

  bf16x8 qf[4];
  {
    const unsigned short* qrow = &Qp[((size_t)bh * TGT + T0 + l15) * HD];
    for (int kf = 0; kf < 4; ++kf)
      qf[kf] = *(const bf16x8*)(&qrow[kf * 32 + l4 * 8]);
  }

  f32x4 acc_o[8] = {};
  float m_run = -INFINITY, l_run = 0.f;

  const unsigned short* kbh = Kp + (size_t)bh * JPH * HD;
  const unsigned short* vbh = VpT + (size_t)bh * HD * JPH;

  for (int jt = 0; jt < 16; ++jt) {
    const int j0 = jt * 64;
    // stage K rows [w*16, w*16+16): 4 x global_load_lds (4 rows each)
    for (int it = 0; it < 4; ++it) {
      int rb = w * 16 + it * 4;
      int row = rb + l4;
      const unsigned char* g =
          (const unsigned char*)(kbh + (size_t)(j0 + row) * HD);
      g += (l15 * 16) ^ ((row & 7) << 4);
      gload_lds16(g, &Klds[rb * 128]);
    }
    // stage V rows d in [w*32, w*32+32): 4 x global_load_lds (8 rows each)
    for (int it = 0; it < 4; ++it) {
      int rb = w * 32 + it * 8;
      int d = rb + (lane >> 3);
      const unsigned char* g =
          (const unsigned char*)(vbh + (size_t)d * JPH + j0);
      g += ((lane & 7) * 16) ^ ((d & 7) << 4);
      gload_lds16(g, &Vlds[rb * 64]);
    }
    __syncthreads();

    // S^T = K * Q : lane holds t = l15, j = jf*16 + l4*4 + i
    f32x4 acc_s[4] = {};
    for (int jf = 0; jf < 4; ++jf) {
      const int j = jf * 16 + l15;
      for (int kf = 0; kf < 4; ++kf) {
        int byteoff = (j * 256 + (kf * 32 + l4 * 8) * 2) ^ ((j & 7) << 4);
        bf16x8 kfr = *(const bf16x8*)((const unsigned char*)Klds + byteoff);
        acc_s[jf] = __builtin_amdgcn_mfma_f32_16x16x32_bf16(
            kfr, qf[kf], acc_s[jf], 0, 0, 0);
      }
    }

    // online softmax over this lane's row (t = l15)
    float pmax = -INFINITY;
    for (int jf = 0; jf < 4; ++jf)
      for (int i = 0; i < 4; ++i) pmax = fmaxf(pmax, acc_s[jf][i]);
    pmax = fmaxf(pmax, __shfl_xor(pmax, 16, 64));
    pmax = fmaxf(pmax, __shfl_xor(pmax, 32, 64));
    const float m_new = fmaxf(m_run, pmax);
    const float alpha = exp2f((m_run - m_new) * LOG2E);
    float psum = 0.f;
    for (int jf = 0; jf < 4; ++jf) {
      float p0 = exp2f((acc_s[jf][0] - m_new) * LOG2E);
      float p1 = exp2f((acc_s[jf][1] - m_new) * LOG2E);
      float p2 = exp2f((acc_s[jf][2] - m_new) * LOG2E);
      float p3 = exp2f((acc_s[jf][3] - m_new) * LOG2E);
      psum += (p0 + p1) + (p2 + p3);
      ushort4 pk;
      pk.x = f2bf(p0); pk.y = f2bf(p1); pk.z = f2bf(p2); pk.w = f2bf(p3);
      int byteoff = (w * 2048 + l15 * 128 + (jf * 16 + l4 * 4) * 2) ^ ((l15 & 7) << 4);
      *(ushort4*)((unsigned char*)Plds + byteoff) = pk;
    }
    psum += __shfl_xor(psum, 16, 64);
    psum += __shfl_xor(psum, 32, 64);
    l_run = l_run * alpha + psum;
    m_run = m_new;

    // rescale O: acc_o[df][i] is row t = l4*4+i; its alpha lives at lane
    // with l15 == l4*4+i. Broadcast before scaling.
    float alphar[4];
    for (int i = 0; i < 4; ++i)
      alphar[i] = __shfl(alpha, (lane & 48) | (l4 * 4 + i), 64);
    for (int df = 0; df < 8; ++df) {
      acc_o[df][0] *= alphar[0]; acc_o[df][1] *= alphar[1];
      acc_o[df][2] *= alphar[2]; acc_o[df][3] *= alphar[3];
    }

    // O += P * V
    for (int kf2 = 0; kf2 < 2; ++kf2) {
      int poff = (w * 2048 + l15 * 128 + (kf2 * 32 + l4 * 8) * 2) ^ ((l15 & 7) << 4);
      bf16x8 pf = *(const bf16x8*)((const unsigned char*)Plds + poff);
      for (int df = 0; df < 8; ++df) {
        int d = df * 16 + l15;
        int voff = (d * 128 + (kf2 * 32 + l4 * 8) * 2) ^ ((d & 7) << 4);
        bf16x8 vf = *(const bf16x8*)((const unsigned char*)Vlds + voff);
        acc_o[df] = __builtin_amdgcn_mfma_f32_16x16x32_bf16(
            pf, vf, acc_o[df], 0, 0, 0);
      }
    }
    __syncthreads();
  }

  // finalize: PV output rows are t = T0 + l4*4 + i; l_run lives at lane l15==t
  const float li = 1.0f / l_run;
  float linv[4];
  for (int i = 0; i < 4; ++i)
    linv[i] = __shfl(li, (lane & 48) | (l4 * 4 + i), 64);

  const int b = bh >> 3, h = bh & 7;
  for (int df = 0; df < 8; ++df)
    for (int i = 0; i < 4; ++i) {
      int t = T0 + l4 * 4 + i;
      int d = df * 16 + l15;
      O[((size_t)b * TGT + t) * DM + h * HD + d] = f2bf(acc_o[df][i] * linv[i]);
    }
}

// ---------------------------------------------------------------------------
// Output projection: out = O @ Wo + bo (bf16 A/B, fp32 out)
// grid (8 n-tiles, 16 m-tiles), 256 thr
// ---------------------------------------------------------------------------
__global__ __launch_bounds__(256) void oproj_kernel(
    const unsigned short* __restrict__ Oin, const unsigned short* __restrict__ WoT,
    const float* __restrict__ bo, float* __restrict__ out) {
  __shared__ unsigned short Alds[128 * 40];
  __shared__ unsigned short Blds[128 * 40];
  const int tid = threadIdx.x, lane = tid & 63, w = tid >> 6;
  const int wm = w >> 1, wn = w & 1;
  const int n0 = blockIdx.x * 128, m0 = blockIdx.y * 128;
  const int l15 = lane & 15, l4 = lane >> 4;
  f32x4 acc[4][4] = {};
  for (int k0 = 0; k0 < DM; k0 += 32) {
    const int c8 = (tid & 3) * 8;
    const int rb = tid >> 2;
    for (int it = 0; it < 2; ++it) {
      int r = rb + it * 64;
      *(uint4*)(&Alds[r * 40 + c8]) =
          *(const uint4*)(&Oin[(size_t)(m0 + r) * DM + k0 + c8]);
      *(uint4*)(&Blds[r * 40 + c8]) =
          *(const uint4*)(&WoT[(size_t)(n0 + r) * DM + k0 + c8]);
    }
    __syncthreads();
    bf16x8 af[4], bfr[4];
    for (int f = 0; f < 4; ++f) {
      af[f]  = *(const bf16x8*)(&Alds[(wm * 64 + f * 16 + l15) * 40 + l4 * 8]);
      bfr[f] = *(const bf16x8*)(&Blds[(wn * 64 + f * 16 + l15) * 40 + l4 * 8]);
    }
    for (int fm = 0; fm < 4; ++fm)
      for (int fn = 0; fn < 4; ++fn)
        acc[fm][fn] = __builtin_amdgcn_mfma_f32_16x16x32_bf16(
            af[fm], bfr[fn], acc[fm][fn], 0, 0, 0);
    __syncthreads();
  }
  for (int fm = 0; fm < 4; ++fm)
    for (int fn = 0; fn < 4; ++fn) {
      int nn = n0 + wn * 64 + fn * 16 + l15;
      float bs = bo[nn];
      for (int i = 0; i < 4; ++i) {
        int mm = m0 + wm * 64 + fm * 16 + l4 * 4 + i;
        out[(size_t)mm * DM + nn] = acc[fm][fn][i] + bs;
      }
    }
}

// ---------------------------------------------------------------------------
extern "C" void kernel_launch(void* const* d_in, const int* in_sizes, int n_in,
                              void* d_out, int out_size, void* d_ws,
                              size_t ws_size, hipStream_t stream) {
  const float* q  = (const float*)d_in[0];
  const float* k  = (const float*)d_in[1];
  const float* v  = (const float*)d_in[2];
  const float* Wq = (const float*)d_in[3];
  const float* bq = (const float*)d_in[4];
  const float* Wk = (const float*)d_in[5];
  const float* bk = (const float*)d_in[6];
  const float* Wv = (const float*)d_in[7];
  const float* bv = (const float*)d_in[8];
  const float* Wo = (const float*)d_in[9];
  const float* bo = (const float*)d_in[10];
  float* out = (float*)d_out;

  unsigned short* WT  = (unsigned short*)d_ws;      // 4 x 1024x1024 bf16 (8 MB)
  unsigned short* Qp  = WT + (size_t)4 * DM * DM;   // [2][8][1024][128] (4 MB)
  unsigned short* Kp  = Qp + (size_t)2 * DM * DM;   // [16][1024][128]   (4 MB)
  unsigned short* VpT = Kp + (size_t)2 * DM * DM;   // [16][128][1024]   (4 MB)
  unsigned short* Obf = VpT + (size_t)2 * DM * DM;  // [2][1024][1024]   (4 MB)

  hipLaunchKernelGGL(wconv_kernel, dim3(16, 16, 4), dim3(256), 0, stream,
                     Wq, Wk, Wv, Wo, WT);
  hipLaunchKernelGGL(proj_kernel, dim3(8, 16), dim3(256), 0, stream,
                     q, k, v, WT, bq, bk, bv, Qp, Kp, VpT, 0);
  hipLaunchKernelGGL(proj_kernel, dim3(8, 16), dim3(256), 0, stream,
                     q, k, v, WT, bq, bk, bv, Qp, Kp, VpT, 1);
  hipLaunchKernelGGL(proj_kernel, dim3(8, 16), dim3(256), 0, stream,
                     q, k, v, WT, bq, bk, bv, Qp, Kp, VpT, 2);
  hipLaunchKernelGGL(attn_kernel, dim3(16, 16), dim3(256), 0, stream,
                     Qp, Kp, VpT, Obf);
  hipLaunchKernelGGL(oproj_kernel, dim3(8, 16), dim3(256), 0, stream,
                     Obf, WT + (size_t)3 * DM * DM, bo, out);
}

// Round 3
// 114.916 us; speedup vs baseline: 1.5001x; 1.5001x over previous
//
#include <hip/hip_runtime.h>
#include <hip/hip_bf16.h>
#include <stdint.h>

#define DM 1024
#define HD 128
#define NH 8
#define NB 2
#define TGT 1024
#define SRC 8192
#define JPH 1024
#define LOG2E 1.4426950408889634f

typedef __attribute__((ext_vector_type(8))) short bf16x8;
typedef __attribute__((ext_vector_type(4))) float f32x4;

__device__ __forceinline__ unsigned short f2bf(float f) {
  __hip_bfloat16 h = __float2bfloat16(f);
  return __builtin_bit_cast(unsigned short, h);
}

__device__ __forceinline__ void gload_lds16(const void* g, void* l) {
  __builtin_amdgcn_global_load_lds(
      (const __attribute__((address_space(1))) unsigned int*)g,
      (__attribute__((address_space(3))) unsigned int*)l, 16, 0, 0);
}

// ---------------------------------------------------------------------------
// Weight transpose + fp32->bf16 convert: WT[n][k] = bf16(W[k][n])
// grid (16,16,4) block 256
// ---------------------------------------------------------------------------
__global__ __launch_bounds__(256) void wconv_kernel(
    const float* __restrict__ Wq, const float* __restrict__ Wk,
    const float* __restrict__ Wv, const float* __restrict__ Wo,
    unsigned short* __restrict__ WTout) {
  __shared__ float tile[64][65];
  const float* W = (blockIdx.z == 0) ? Wq : (blockIdx.z == 1) ? Wk
                   : (blockIdx.z == 2) ? Wv : Wo;
  unsigned short* WT = WTout + (size_t)blockIdx.z * DM * DM;
  const int k0 = blockIdx.x * 64, n0 = blockIdx.y * 64;
  const int tid = threadIdx.x;
  const int tr = tid >> 4, tc = (tid & 15) * 4;
  for (int it = 0; it < 4; ++it) {
    int r = tr + it * 16;
    float4 vv = *(const float4*)(&W[(size_t)(k0 + r) * DM + n0 + tc]);
    tile[r][tc] = vv.x; tile[r][tc + 1] = vv.y;
    tile[r][tc + 2] = vv.z; tile[r][tc + 3] = vv.w;
  }
  __syncthreads();
  for (int it = 0; it < 4; ++it) {
    int n = tr + it * 16;
    ushort4 o;
    o.x = f2bf(tile[tc + 0][n]); o.y = f2bf(tile[tc + 1][n]);
    o.z = f2bf(tile[tc + 2][n]); o.w = f2bf(tile[tc + 3][n]);
    *(ushort4*)(&WT[(size_t)(n0 + n) * DM + k0 + tc]) = o;
  }
}

// ---------------------------------------------------------------------------
// Fused projection GEMM, all 3 modes in one dispatch. grid: 384 blocks.
//   bid 0..127  : mode 0, Q = q @ Wq + bq -> Qp[b][h][t][d] (scaled)
//   bid 128..255: mode 1, K rows j=h+8j'  -> Kp[bh][j'][d]
//   bid 256..383: mode 2, V rows j=h+8j'  -> VpT[bh][d][j']
// 128x128 tile, BK=64, double-buffered LDS pipeline:
//   A: fp32 global -> regs (issued early) -> cvt -> swizzled ds_write
//   B: global_load_lds w=16, pre-swizzled global source (rule #21)
// ---------------------------------------------------------------------------
__global__ __launch_bounds__(256) void proj_fused_kernel(
    const float* __restrict__ q, const float* __restrict__ k,
    const float* __restrict__ v, const unsigned short* __restrict__ WTall,
    const float* __restrict__ bq, const float* __restrict__ bk,
    const float* __restrict__ bv, unsigned short* __restrict__ Qp,
    unsigned short* __restrict__ Kp, unsigned short* __restrict__ VpT) {
  __shared__ unsigned short Ab[2][128 * 64];  // 16 KB each, XOR-swizzled
  __shared__ unsigned short Bb[2][128 * 64];
  const int tid = threadIdx.x, lane = tid & 63, w = tid >> 6;
  const int wm = w >> 1, wn = w & 1;
  const int l15 = lane & 15, l4 = lane >> 4;

  const int bid = blockIdx.x;
  const int mode = bid >> 7;
  const int sub = bid & 127;
  const float* Asrc;
  const unsigned short* WT;
  const float* bias;
  int nbase, bh = 0, Mtile;
  if (mode == 0) {
    Asrc = q; WT = WTall; bias = bq;
    Mtile = sub >> 3; nbase = (sub & 7) * 128;
  } else {
    bh = sub >> 3; Mtile = sub & 7;
    nbase = (bh & 7) * 128;
    if (mode == 1) { Asrc = k; WT = WTall + (size_t)DM * DM; bias = bk; }
    else           { Asrc = v; WT = WTall + (size_t)2 * DM * DM; bias = bv; }
  }

  float4 areg[4][2];
  auto loadA = [&](int t) {
    const int kk0 = t * 64;
    for (int p = 0; p < 4; ++p) {
      int r = p * 32 + (tid >> 3);
      size_t grow;
      if (mode == 0) grow = (size_t)(Mtile * 128 + r);
      else grow = (size_t)(bh >> 3) * SRC + (size_t)(bh & 7) +
                  8u * (size_t)(Mtile * 128 + r);
      const float* src = &Asrc[grow * DM + kk0 + (tid & 7) * 8];
      areg[p][0] = *(const float4*)(src);
      areg[p][1] = *(const float4*)(src + 4);
    }
  };
  auto writeA = [&](int buf) {
    for (int p = 0; p < 4; ++p) {
      int r = p * 32 + (tid >> 3);
      bf16x8 pk;
      pk[0] = (short)f2bf(areg[p][0].x); pk[1] = (short)f2bf(areg[p][0].y);
      pk[2] = (short)f2bf(areg[p][0].z); pk[3] = (short)f2bf(areg[p][0].w);
      pk[4] = (short)f2bf(areg[p][1].x); pk[5] = (short)f2bf(areg[p][1].y);
      pk[6] = (short)f2bf(areg[p][1].z); pk[7] = (short)f2bf(areg[p][1].w);
      int off = r * 128 + (((tid & 7) * 16) ^ ((r & 7) << 4));
      *(bf16x8*)((unsigned char*)Ab[buf] + off) = pk;
    }
  };
  auto stageB = [&](int t, int buf) {
    const int kk0 = t * 64;
    for (int it = 0; it < 4; ++it) {
      int gi = w * 4 + it;              // 0..15: 8 rows each
      int row = gi * 8 + (lane >> 3);
      const unsigned char* g =
          (const unsigned char*)&WT[(size_t)(nbase + row) * DM + kk0];
      g += ((lane & 7) * 16) ^ ((row & 7) << 4);
      gload_lds16(g, (unsigned char*)Bb[buf] + gi * 1024);
    }
  };

  f32x4 acc[4][4] = {};

  loadA(0);
  stageB(0, 0);
  writeA(0);        // compiler inserts vmcnt waits for areg
  __syncthreads();  // drains gload_lds (vmcnt 0) + ds_writes

  for (int t = 0; t < 16; ++t) {
    const int cur = t & 1;
    if (t < 15) { loadA(t + 1); stageB(t + 1, cur ^ 1); }

    bf16x8 af[4][2], bfr[4][2];
    for (int f = 0; f < 4; ++f)
      for (int kk = 0; kk < 2; ++kk) {
        int ra = wm * 64 + f * 16 + l15;
        int ka = (kk * 64 + l4 * 16) ^ ((ra & 7) << 4);
        af[f][kk] = *(const bf16x8*)((const unsigned char*)Ab[cur] + ra * 128 + ka);
        int rb = wn * 64 + f * 16 + l15;
        int kb = (kk * 64 + l4 * 16) ^ ((rb & 7) << 4);
        bfr[f][kk] = *(const bf16x8*)((const unsigned char*)Bb[cur] + rb * 128 + kb);
      }
    for (int kk = 0; kk < 2; ++kk)
      for (int fm = 0; fm < 4; ++fm)
        for (int fn = 0; fn < 4; ++fn)
          acc[fm][fn] = __builtin_amdgcn_mfma_f32_16x16x32_bf16(
              af[fm][kk], bfr[fn][kk], acc[fm][fn], 0, 0, 0);

    if (t < 15) writeA(cur ^ 1);
    __syncthreads();
  }

  // epilogue (same as round-2 proj)
  for (int fm = 0; fm < 4; ++fm) {
    for (int fn = 0; fn < 4; ++fn) {
      const int mloc = wm * 64 + fm * 16 + l4 * 4;
      const int nloc = wn * 64 + fn * 16 + l15;
      const float bs = bias[nbase + nloc];
      if (mode == 2) {
        const int d = nloc;
        const int jp = Mtile * 128 + mloc;
        ushort4 o;
        o.x = f2bf(acc[fm][fn][0] + bs); o.y = f2bf(acc[fm][fn][1] + bs);
        o.z = f2bf(acc[fm][fn][2] + bs); o.w = f2bf(acc[fm][fn][3] + bs);
        *(ushort4*)(&VpT[((size_t)bh * HD + d) * JPH + jp]) = o;
      } else if (mode == 1) {
        for (int i = 0; i < 4; ++i) {
          int jp = Mtile * 128 + mloc + i;
          Kp[((size_t)bh * JPH + jp) * HD + nloc] = f2bf(acc[fm][fn][i] + bs);
        }
      } else {
        for (int i = 0; i < 4; ++i) {
          int mg = Mtile * 128 + mloc + i;
          int bb = mg >> 10, tt = mg & 1023;
          int ng = nbase + nloc;
          int h = ng >> 7, d = ng & 127;
          Qp[(((size_t)bb * NH + h) * TGT + tt) * HD + d] =
              f2bf((acc[fm][fn][i] + bs) * 0.08838834764831845f);
        }
      }
    }
  }
}

// ---------------------------------------------------------------------------
// Flash attention per (b,h), sparse j = h + 8*j'. grid (16 tq, 16 bh), 256 thr
// Swapped QK^T: mfma(A=K, B=Q) -> lane owns one query row's scores (t=lane&15).
// acc_o rows are t=(lane>>4)*4+i -> alpha shfl-broadcast before rescale.
// ---------------------------------------------------------------------------
__global__ __launch_bounds__(256) void attn_kernel(
    const unsigned short* __restrict__ Qp, const unsigned short* __restrict__ Kp,
    const unsigned short* __restrict__ VpT, unsigned short* __restrict__ O) {
  __shared__ unsigned short Klds[64 * 128];   // [j][d] swizzled, 16 KB
  __shared__ unsigned short Vlds[128 * 64];   // [d][j] swizzled, 16 KB
  __shared__ unsigned short Plds[4 * 16 * 64];// per-wave [t][j] swizzled, 8 KB
  const int tid = threadIdx.x, lane = tid & 63, w = tid >> 6;
  const int tq = blockIdx.x, bh = blockIdx.y;
  const int T0 = tq * 64 + w * 16;
  const int l15 = lane & 15, l4 = lane >> 4;

  bf16x8 qf[4];
  {
    const unsigned short* qrow = &Qp[((size_t)bh * TGT + T0 + l15) * HD];
    for (int kf = 0; kf < 4; ++kf)
      qf[kf] = *(const bf16x8*)(&qrow[kf * 32 + l4 * 8]);
  }

  f32x4 acc_o[8] = {};
  float m_run = -INFINITY, l_run = 0.f;

  const unsigned short* kbh = Kp + (size_t)bh * JPH * HD;
  const unsigned short* vbh = VpT + (size_t)bh * HD * JPH;

  for (int jt = 0; jt < 16; ++jt) {
    const int j0 = jt * 64;
    for (int it = 0; it < 4; ++it) {
      int rb = w * 16 + it * 4;
      int row = rb + l4;
      const unsigned char* g =
          (const unsigned char*)(kbh + (size_t)(j0 + row) * HD);
      g += (l15 * 16) ^ ((row & 7) << 4);
      gload_lds16(g, &Klds[rb * 128]);
    }
    for (int it = 0; it < 4; ++it) {
      int rb = w * 32 + it * 8;
      int d = rb + (lane >> 3);
      const unsigned char* g =
          (const unsigned char*)(vbh + (size_t)d * JPH + j0);
      g += ((lane & 7) * 16) ^ ((d & 7) << 4);
      gload_lds16(g, &Vlds[rb * 64]);
    }
    __syncthreads();

    f32x4 acc_s[4] = {};
    for (int jf = 0; jf < 4; ++jf) {
      const int j = jf * 16 + l15;
      for (int kf = 0; kf < 4; ++kf) {
        int byteoff = (j * 256 + (kf * 32 + l4 * 8) * 2) ^ ((j & 7) << 4);
        bf16x8 kfr = *(const bf16x8*)((const unsigned char*)Klds + byteoff);
        acc_s[jf] = __builtin_amdgcn_mfma_f32_16x16x32_bf16(
            kfr, qf[kf], acc_s[jf], 0, 0, 0);
      }
    }

    float pmax = -INFINITY;
    for (int jf = 0; jf < 4; ++jf)
      for (int i = 0; i < 4; ++i) pmax = fmaxf(pmax, acc_s[jf][i]);
    pmax = fmaxf(pmax, __shfl_xor(pmax, 16, 64));
    pmax = fmaxf(pmax, __shfl_xor(pmax, 32, 64));
    const float m_new = fmaxf(m_run, pmax);
    const float alpha = exp2f((m_run - m_new) * LOG2E);
    float psum = 0.f;
    for (int jf = 0; jf < 4; ++jf) {
      float p0 = exp2f((acc_s[jf][0] - m_new) * LOG2E);
      float p1 = exp2f((acc_s[jf][1] - m_new) * LOG2E);
      float p2 = exp2f((acc_s[jf][2] - m_new) * LOG2E);
      float p3 = exp2f((acc_s[jf][3] - m_new) * LOG2E);
      psum += (p0 + p1) + (p2 + p3);
      ushort4 pk;
      pk.x = f2bf(p0); pk.y = f2bf(p1); pk.z = f2bf(p2); pk.w = f2bf(p3);
      int byteoff = (w * 2048 + l15 * 128 + (jf * 16 + l4 * 4) * 2) ^ ((l15 & 7) << 4);
      *(ushort4*)((unsigned char*)Plds + byteoff) = pk;
    }
    psum += __shfl_xor(psum, 16, 64);
    psum += __shfl_xor(psum, 32, 64);
    l_run = l_run * alpha + psum;
    m_run = m_new;

    float alphar[4];
    for (int i = 0; i < 4; ++i)
      alphar[i] = __shfl(alpha, (lane & 48) | (l4 * 4 + i), 64);
    for (int df = 0; df < 8; ++df) {
      acc_o[df][0] *= alphar[0]; acc_o[df][1] *= alphar[1];
      acc_o[df][2] *= alphar[2]; acc_o[df][3] *= alphar[3];
    }

    for (int kf2 = 0; kf2 < 2; ++kf2) {
      int poff = (w * 2048 + l15 * 128 + (kf2 * 32 + l4 * 8) * 2) ^ ((l15 & 7) << 4);
      bf16x8 pf = *(const bf16x8*)((const unsigned char*)Plds + poff);
      for (int df = 0; df < 8; ++df) {
        int d = df * 16 + l15;
        int voff = (d * 128 + (kf2 * 32 + l4 * 8) * 2) ^ ((d & 7) << 4);
        bf16x8 vf = *(const bf16x8*)((const unsigned char*)Vlds + voff);
        acc_o[df] = __builtin_amdgcn_mfma_f32_16x16x32_bf16(
            pf, vf, acc_o[df], 0, 0, 0);
      }
    }
    __syncthreads();
  }

  const float li = 1.0f / l_run;
  float linv[4];
  for (int i = 0; i < 4; ++i)
    linv[i] = __shfl(li, (lane & 48) | (l4 * 4 + i), 64);

  const int b = bh >> 3, h = bh & 7;
  for (int df = 0; df < 8; ++df)
    for (int i = 0; i < 4; ++i) {
      int t = T0 + l4 * 4 + i;
      int d = df * 16 + l15;
      O[((size_t)b * TGT + t) * DM + h * HD + d] = f2bf(acc_o[df][i] * linv[i]);
    }
}

// ---------------------------------------------------------------------------
// Output projection: out = O @ Wo + bo. Same pipelined template as proj_fused
// but both operands already bf16 -> pure global_load_lds staging.
// grid (8 n-tiles, 16 m-tiles), 256 thr
// ---------------------------------------------------------------------------
__global__ __launch_bounds__(256) void oproj_kernel(
    const unsigned short* __restrict__ Oin, const unsigned short* __restrict__ WoT,
    const float* __restrict__ bo, float* __restrict__ out) {
  __shared__ unsigned short Ab[2][128 * 64];
  __shared__ unsigned short Bb[2][128 * 64];
  const int tid = threadIdx.x, lane = tid & 63, w = tid >> 6;
  const int wm = w >> 1, wn = w & 1;
  const int n0 = blockIdx.x * 128, m0 = blockIdx.y * 128;
  const int l15 = lane & 15, l4 = lane >> 4;

  auto stage = [&](const unsigned short* src, int rbase, int t, unsigned short* lds) {
    const int kk0 = t * 64;
    for (int it = 0; it < 4; ++it) {
      int gi = w * 4 + it;
      int row = gi * 8 + (lane >> 3);
      const unsigned char* g =
          (const unsigned char*)&src[(size_t)(rbase + row) * DM + kk0];
      g += ((lane & 7) * 16) ^ ((row & 7) << 4);
      gload_lds16(g, (unsigned char*)lds + gi * 1024);
    }
  };

  f32x4 acc[4][4] = {};
  stage(Oin, m0, 0, Ab[0]);
  stage(WoT, n0, 0, Bb[0]);
  __syncthreads();

  for (int t = 0; t < 16; ++t) {
    const int cur = t & 1;
    if (t < 15) {
      stage(Oin, m0, t + 1, Ab[cur ^ 1]);
      stage(WoT, n0, t + 1, Bb[cur ^ 1]);
    }
    bf16x8 af[4][2], bfr[4][2];
    for (int f = 0; f < 4; ++f)
      for (int kk = 0; kk < 2; ++kk) {
        int ra = wm * 64 + f * 16 + l15;
        int ka = (kk * 64 + l4 * 16) ^ ((ra & 7) << 4);
        af[f][kk] = *(const bf16x8*)((const unsigned char*)Ab[cur] + ra * 128 + ka);
        int rb = wn * 64 + f * 16 + l15;
        int kb = (kk * 64 + l4 * 16) ^ ((rb & 7) << 4);
        bfr[f][kk] = *(const bf16x8*)((const unsigned char*)Bb[cur] + rb * 128 + kb);
      }
    for (int kk = 0; kk < 2; ++kk)
      for (int fm = 0; fm < 4; ++fm)
        for (int fn = 0; fn < 4; ++fn)
          acc[fm][fn] = __builtin_amdgcn_mfma_f32_16x16x32_bf16(
              af[fm][kk], bfr[fn][kk], acc[fm][fn], 0, 0, 0);
    __syncthreads();
  }

  for (int fm = 0; fm < 4; ++fm)
    for (int fn = 0; fn < 4; ++fn) {
      int nn = n0 + wn * 64 + fn * 16 + l15;
      float bs = bo[nn];
      for (int i = 0; i < 4; ++i) {
        int mm = m0 + wm * 64 + fm * 16 + l4 * 4 + i;
        out[(size_t)mm * DM + nn] = acc[fm][fn][i] + bs;
      }
    }
}

// ---------------------------------------------------------------------------
extern "C" void kernel_launch(void* const* d_in, const int* in_sizes, int n_in,
                              void* d_out, int out_size, void* d_ws,
                              size_t ws_size, hipStream_t stream) {
  const float* q  = (const float*)d_in[0];
  const float* k  = (const float*)d_in[1];
  const float* v  = (const float*)d_in[2];
  const float* Wq = (const float*)d_in[3];
  const float* bq = (const float*)d_in[4];
  const float* Wk = (const float*)d_in[5];
  const float* bk = (const float*)d_in[6];
  const float* Wv = (const float*)d_in[7];
  const float* bv = (const float*)d_in[8];
  const float* Wo = (const float*)d_in[9];
  const float* bo = (const float*)d_in[10];
  float* out = (float*)d_out;

  unsigned short* WT  = (unsigned short*)d_ws;      // 4 x 1024x1024 bf16 (8 MB)
  unsigned short* Qp  = WT + (size_t)4 * DM * DM;   // [2][8][1024][128] (4 MB)
  unsigned short* Kp  = Qp + (size_t)2 * DM * DM;   // [16][1024][128]   (4 MB)
  unsigned short* VpT = Kp + (size_t)2 * DM * DM;   // [16][128][1024]   (4 MB)
  unsigned short* Obf = VpT + (size_t)2 * DM * DM;  // [2][1024][1024]   (4 MB)

  hipLaunchKernelGGL(wconv_kernel, dim3(16, 16, 4), dim3(256), 0, stream,
                     Wq, Wk, Wv, Wo, WT);
  hipLaunchKernelGGL(proj_fused_kernel, dim3(384), dim3(256), 0, stream,
                     q, k, v, WT, bq, bk, bv, Qp, Kp, VpT);
  hipLaunchKernelGGL(attn_kernel, dim3(16, 16), dim3(256), 0, stream,
                     Qp, Kp, VpT, Obf);
  hipLaunchKernelGGL(oproj_kernel, dim3(8, 16), dim3(256), 0, stream,
                     Obf, WT + (size_t)3 * DM * DM, bo, out);
}